// Round 13
// baseline (69.221 us; speedup 1.0000x reference)
//
#include <hip/hip_runtime.h>
#include <math.h>

// Problem dims (fixed by the reference)
#define B_DIM 4096
#define F_DIM 1024
#define C_DIM 2047
#define C_PAD 2048
#define DEPTH 11

#define LOG2E 1.4426950408889634f

typedef __attribute__((ext_vector_type(8))) short bf16x8;
typedef __attribute__((ext_vector_type(4))) float f32x4;

#define AS1(p) ((const __attribute__((address_space(1))) void*)(p))
#define AS3(p) ((__attribute__((address_space(3))) void*)(p))

#define XTOT (B_DIM * F_DIM)          // 4194304
#define WTOT (C_PAD * F_DIM)          // 2097152

// ---------------------------------------------------------------------------
// bf16 helpers (RNE)
// ---------------------------------------------------------------------------
__device__ __forceinline__ unsigned short f2bf(float f) {
    unsigned int u = __float_as_uint(f);
    unsigned int r = (u + 0x7fffu + ((u >> 16) & 1u)) >> 16;
    return (unsigned short)r;
}
__device__ __forceinline__ float bf2f(unsigned short u) {
    return __uint_as_float(((unsigned int)u) << 16);
}

// pk position remap (bank-conflict-free LDS layout), n = node+1 in [1,2048):
//   n < 512           : pos = n                      (scalar-access levels)
//   512 <= n < 1024   : pos = 512 + (n&1)*256 + ((n-512)>>1)    (level 9)
//   1024 <= n         : pos = 1024 + (n&3)*256 + ((n-1024)>>2)  (leaves)
__device__ __forceinline__ int pk_pos(int n) {
    if (n < 512) return n;
    if (n < 1024) return 512 + (n & 1) * 256 + ((n - 512) >> 1);
    return 1024 + (n & 3) * 256 + ((n - 1024) >> 2);
}

// ---------------------------------------------------------------------------
// Fused convert + pack:
//   x (B,F) f32 -> xb bf16 ; w (C,F) f32 -> wb bf16 (padded to C_PAD rows)
//   pairs tree edges -> pk SoA [4][2048], de-interleaved layout, * LOG2E
// ---------------------------------------------------------------------------
__global__ __launch_bounds__(256) void cvt_pack_kernel(
    const float* __restrict__ x, const float* __restrict__ w,
    const float* __restrict__ pairs,
    unsigned short* __restrict__ xb, unsigned short* __restrict__ wb,
    float* __restrict__ pk)
{
    const int i = (blockIdx.x * 256 + threadIdx.x) * 4;
    if (i < XTOT) {
        float4 v = *(const float4*)(x + i);
        ushort4 h;
        h.x = f2bf(v.x); h.y = f2bf(v.y); h.z = f2bf(v.z); h.w = f2bf(v.w);
        *(ushort4*)(xb + i) = h;
    } else if (i < XTOT + WTOT) {
        const int j = i - XTOT;                    // < WTOT
        const int row = j >> 10;                   // F = 1024
        ushort4 h = {0, 0, 0, 0};
        if (row < C_DIM) {
            float4 v = *(const float4*)(w + j);
            h.x = f2bf(v.x); h.y = f2bf(v.y); h.z = f2bf(v.z); h.w = f2bf(v.w);
        }
        *(ushort4*)(wb + j) = h;
    } else {
        const int c0 = i - XTOT - WTOT;            // 0..2044 step 4
#pragma unroll
        for (int t = 0; t < 4; ++t) {
            const int c = c0 + t;
            if (c >= 1 && c < C_DIM) {
                const int p = (c - 1) >> 1;
                float4 v = *(const float4*)(pairs + ((size_t)p * C_DIM + c) * 4);
                const int pos = pk_pos(c + 1);
                pk[pos]        = v.x * LOG2E;
                pk[pos + 2048] = v.y * LOG2E;
                pk[pos + 4096] = v.z * LOG2E;
                pk[pos + 6144] = v.w * LOG2E;
            }
        }
    }
}

// ---------------------------------------------------------------------------
// MFMA GEMM, 2-phase pipeline:
//   eb[r*2048 + c + 1] = bf16( (x @ W^T + bias)[r,c] * LOG2E )
// 128x128 tile, K-tile = 64, double-buffered LDS, one barrier per K-tile.
// Conflict-free chunk swizzle s(row)=(row>>1)&3.
// XCD mapping: each XCD owns an 8bm x 8bn chunk (4 MB working set = L2 size);
// eb written with NONTEMPORAL stores so the stream doesn't evict operands.
// ---------------------------------------------------------------------------
__global__ __launch_bounds__(256) void gemm_bf16_kernel(
    const unsigned short* __restrict__ xb, const unsigned short* __restrict__ wb,
    const float* __restrict__ bias, unsigned short* __restrict__ eb)
{
    __shared__ unsigned short smem[2][2][2][4096];

    const int tid  = threadIdx.x;
    const int lane = tid & 63;
    const int wave = tid >> 6;
    const int wr = wave >> 1, wc = wave & 1;

    const int lin   = blockIdx.x + blockIdx.y * gridDim.x;   // 0..511
    const int xcd   = lin & 7, local = lin >> 3;             // 8 x 64
    const int bm = (xcd >> 1) * 8 + (local >> 3);            // 0..31
    const int bn = (xcd & 1) * 8 + (local & 7);              // 0..15

    f32x4 acc[4][4] = {};

    const int r0 = tid >> 2,       c0 = tid & 3;
    const int r1 = 64 + (tid >> 2);
    const int sc0 = ((c0 ^ ((r0 >> 1) & 3)) << 3);
    const int sc1 = ((c0 ^ ((r1 >> 1) & 3)) << 3);

    const size_t arow0 = (size_t)(bm * 128 + r0) * F_DIM;
    const size_t arow1 = (size_t)(bm * 128 + r1) * F_DIM;
    const size_t brow0 = (size_t)(bn * 128 + r0) * F_DIM;
    const size_t brow1 = (size_t)(bn * 128 + r1) * F_DIM;

    const int lb0 = wave * 512;
    const int lb1 = 2048 + wave * 512;

    const int fra = wr * 64 + (lane & 15);
    const int frb = wc * 64 + (lane & 15);
    const int kc  = lane >> 4;

#define STAGE(buf, kt)                                                          \
    {                                                                           \
        const int kbase = (kt) * 64;                                            \
        _Pragma("unroll")                                                       \
        for (int ks = 0; ks < 2; ++ks) {                                        \
            const int k0 = kbase + ks * 32;                                     \
            __builtin_amdgcn_global_load_lds(AS1(xb + arow0 + k0 + sc0),        \
                AS3(&smem[buf][0][ks][lb0]), 16, 0, 0);                         \
            __builtin_amdgcn_global_load_lds(AS1(xb + arow1 + k0 + sc1),        \
                AS3(&smem[buf][0][ks][lb1]), 16, 0, 0);                         \
            __builtin_amdgcn_global_load_lds(AS1(wb + brow0 + k0 + sc0),        \
                AS3(&smem[buf][1][ks][lb0]), 16, 0, 0);                         \
            __builtin_amdgcn_global_load_lds(AS1(wb + brow1 + k0 + sc1),        \
                AS3(&smem[buf][1][ks][lb1]), 16, 0, 0);                         \
        }                                                                       \
    }

    const int NT = F_DIM / 64;   // 16
    STAGE(0, 0);
    __syncthreads();

    for (int kt = 0; kt < NT; ++kt) {
        const int cur = kt & 1;
        if (kt + 1 < NT) STAGE(cur ^ 1, kt + 1);

#pragma unroll
        for (int ks = 0; ks < 2; ++ks) {
            bf16x8 af[4], bfr[4];
#pragma unroll
            for (int m = 0; m < 4; ++m) {
                const int row = fra + m * 16;
                af[m] = *(const bf16x8*)(&smem[cur][0][ks]
                        [row * 32 + ((kc ^ ((row >> 1) & 3)) << 3)]);
            }
#pragma unroll
            for (int n = 0; n < 4; ++n) {
                const int row = frb + n * 16;
                bfr[n] = *(const bf16x8*)(&smem[cur][1][ks]
                        [row * 32 + ((kc ^ ((row >> 1) & 3)) << 3)]);
            }
#pragma unroll
            for (int m = 0; m < 4; ++m)
#pragma unroll
                for (int n = 0; n < 4; ++n)
                    acc[m][n] = __builtin_amdgcn_mfma_f32_16x16x32_bf16(
                        af[m], bfr[n], acc[m][n], 0, 0, 0);
        }
        __syncthreads();
    }
#undef STAGE

    const int colbase = bn * 128 + wc * 64 + (lane & 15);
    const int rowbase = bm * 128 + wr * 64 + ((lane >> 4) << 2);
#pragma unroll
    for (int m = 0; m < 4; ++m)
#pragma unroll
        for (int n = 0; n < 4; ++n) {
            const int gc = colbase + n * 16;
            if (gc < C_DIM) {
                const float bv = bias[gc];
#pragma unroll
                for (int r = 0; r < 4; ++r)
                    __builtin_nontemporal_store(
                        f2bf((acc[m][n][r] + bv) * LOG2E),
                        &eb[(size_t)(rowbase + m * 16 + r) * C_PAD + gc + 1]);
            }
        }
}

// ---------------------------------------------------------------------------
// Fallback f32 GEMM (only if ws too small) — writes d_out directly
// ---------------------------------------------------------------------------
#define BMF 64
#define BNF 64
#define BKF 16

__global__ __launch_bounds__(256) void gemm_f32_kernel(
    const float* __restrict__ x, const float* __restrict__ w,
    const float* __restrict__ bias, float* __restrict__ e)
{
    __shared__ float As[BKF][BMF];
    __shared__ float Bs[BKF][BNF];
    const int bn = blockIdx.x, bm = blockIdx.y;
    const int tid = threadIdx.x;
    const int tx = tid & 15, ty = tid >> 4;
    const int m0 = ty * 4, n0 = tx * 4;
    const int lrow = tid >> 2, lc4 = (tid & 3) * 4;
    const int gm = bm * BMF + lrow;
    const int gn = bn * BNF + lrow;
    const bool wvalid = (gn < C_DIM);
    const float* xp = x + (size_t)gm * F_DIM + lc4;
    const float* wp = wvalid ? (w + (size_t)gn * F_DIM + lc4) : w;
    float acc[4][4] = {};
    for (int k0 = 0; k0 < F_DIM; k0 += BKF) {
        float4 av = *(const float4*)(xp + k0);
        float4 bv = make_float4(0.f, 0.f, 0.f, 0.f);
        if (wvalid) bv = *(const float4*)(wp + k0);
        As[lc4 + 0][lrow] = av.x; As[lc4 + 1][lrow] = av.y;
        As[lc4 + 2][lrow] = av.z; As[lc4 + 3][lrow] = av.w;
        Bs[lc4 + 0][lrow] = bv.x; Bs[lc4 + 1][lrow] = bv.y;
        Bs[lc4 + 2][lrow] = bv.z; Bs[lc4 + 3][lrow] = bv.w;
        __syncthreads();
#pragma unroll
        for (int k = 0; k < BKF; ++k) {
            float4 a = *(const float4*)&As[k][m0];
            float4 b = *(const float4*)&Bs[k][n0];
            acc[0][0] += a.x * b.x; acc[0][1] += a.x * b.y; acc[0][2] += a.x * b.z; acc[0][3] += a.x * b.w;
            acc[1][0] += a.y * b.x; acc[1][1] += a.y * b.y; acc[1][2] += a.y * b.z; acc[1][3] += a.y * b.w;
            acc[2][0] += a.z * b.x; acc[2][1] += a.z * b.y; acc[2][2] += a.z * b.z; acc[2][3] += a.z * b.w;
            acc[3][0] += a.w * b.x; acc[3][1] += a.w * b.y; acc[3][2] += a.w * b.z; acc[3][3] += a.w * b.w;
        }
        __syncthreads();
    }
    const int gmo = bm * BMF + m0, gno = bn * BNF + n0;
#pragma unroll
    for (int i = 0; i < 4; ++i)
#pragma unroll
        for (int j = 0; j < 4; ++j) {
            int n = gno + j;
            if (n < C_DIM) e[(size_t)(gmo + i) * C_DIM + n] = acc[i][j] + bias[n];
        }
}

// ---------------------------------------------------------------------------
// Tree-CRF: ONE ROW PER WAVE, 8 waves/block (512 thr), grid 512.
// pk staged once per block into LDS (32 KB, de-interleaved layout) — all LDS
// reads are stride-4B across lanes (2-way = conflict-free).
// Emissions arrive PRE-SCALED by log2e; out written with nontemporal stores.
// ---------------------------------------------------------------------------
__device__ __forceinline__ float lse2_2(float a, float b) {
    float m = fmaxf(a, b);
    return m + __log2f(1.f + exp2f(fminf(a, b) - m));
}
__device__ __forceinline__ float sigmoid2(float d) {
    return __builtin_amdgcn_rcpf(1.f + exp2f(-d));
}

__global__ __launch_bounds__(512) void crf_wave_kernel(
    const float* __restrict__ pk,          // SoA [4][2048], de-interleaved
    const unsigned short* __restrict__ eb, // (B, C_PAD) bf16 emissions*LOG2E, +1
    float* __restrict__ out)               // (B, C_DIM) probabilities
{
    __shared__ float spk[4 * 2048];        // 32 KB: planes x,y,z,w

    const int tid  = threadIdx.x;
#pragma unroll
    for (int t = 0; t < 4; ++t) {
        const int idx = t * 2048 + tid * 4;
        *(float4*)(spk + idx) = *(const float4*)(pk + idx);
    }
    __syncthreads();

    const int lane = tid & 63;
    const int row  = blockIdx.x * 8 + (tid >> 6);
    const unsigned short* ebr = eb + (size_t)row * C_PAD;
    float* orow = out + (size_t)row * C_DIM;

    const float* pkx = spk;
    const float* pky = spk + 2048;
    const float* pkz = spk + 4096;
    const float* pkw = spk + 6144;

    // ---------------- ALL emission loads upfront (independent) --------------
    ushort4 evl[4]; ushort2 ev9[4];
    unsigned short ev8[4], ev7[2], ev6s, evu[6];
#pragma unroll
    for (int q = 0; q < 4; ++q)
        evl[q] = *(const ushort4*)(ebr + 1024 + 4 * lane + 256 * q);
#pragma unroll
    for (int q = 0; q < 4; ++q)
        ev9[q] = *(const ushort2*)(ebr + 512 + 2 * lane + 128 * q);
#pragma unroll
    for (int q = 0; q < 4; ++q) ev8[q] = ebr[256 + lane + 64 * q];
#pragma unroll
    for (int q = 0; q < 2; ++q) ev7[q] = ebr[128 + lane + 64 * q];
    ev6s = ebr[64 + lane];
#pragma unroll
    for (int lvl = 0; lvl < 6; ++lvl) evu[lvl] = ebr[(1 << lvl) + lane];

    // ================= UP: leaves (level 10) =================
    // leaf edge n = 1024+4j+r, j = lane+64q -> spk pos 1024 + r*256 + j
    float el[4][4], da9[4][2];
#pragma unroll
    for (int q = 0; q < 4; ++q) {
        const int j = lane + 64 * q;
        float er[4] = {bf2f(evl[q].x), bf2f(evl[q].y), bf2f(evl[q].z), bf2f(evl[q].w)};
        float dm[4];
#pragma unroll
        for (int r = 0; r < 4; ++r) {
            const int pos = 1024 + r * 256 + j;
            const float kx = pkx[pos], ky = pky[pos], kz = pkz[pos], kw = pkw[pos];
            el[q][r] = er[r];
            dm[r] = lse2_2(kz - er[r], kw + er[r])
                  - lse2_2(kx - er[r], ky + er[r]);
        }
        da9[q][0] = dm[0] + dm[1];
        da9[q][1] = dm[2] + dm[3];
    }

    // ================= UP: level 9 =================
    // edge n = 512+2j+r, j = lane+64q -> spk pos 512 + r*256 + j
    float e9[4][2], da8[4];
#pragma unroll
    for (int q = 0; q < 4; ++q) {
        const int j = lane + 64 * q;
        const int p0 = 512 + j, p1 = 768 + j;
        float e0 = bf2f(ev9[q].x), e1 = bf2f(ev9[q].y);
        e9[q][0] = e0; e9[q][1] = e1;
        float dm0 = lse2_2(pkz[p0] - e0, pkw[p0] + e0 + da9[q][0])
                  - lse2_2(pkx[p0] - e0, pky[p0] + e0 + da9[q][0]);
        float dm1 = lse2_2(pkz[p1] - e1, pkw[p1] + e1 + da9[q][1])
                  - lse2_2(pkx[p1] - e1, pky[p1] + e1 + da9[q][1]);
        da8[q] = dm0 + dm1;
    }

    // ================= UP: level 8 =================
    float e8[4], ps8[4];
#pragma unroll
    for (int q = 0; q < 4; ++q) {
        const int bi = 256 + lane + 64 * q;
        float kx = pkx[bi], ky = pky[bi], kz = pkz[bi], kw = pkw[bi];
        float e = bf2f(ev8[q]);
        e8[q] = e;
        float dm = lse2_2(kz - e, kw + e + da8[q])
                 - lse2_2(kx - e, ky + e + da8[q]);
        ps8[q] = dm + __shfl_xor(dm, 1, 64);
    }
    float da7[2];
    {
        const int s = (2 * lane) & 63;
        float t00 = __shfl(ps8[0], s, 64), t01 = __shfl(ps8[1], s, 64);
        float t10 = __shfl(ps8[2], s, 64), t11 = __shfl(ps8[3], s, 64);
        da7[0] = (lane >= 32) ? t01 : t00;
        da7[1] = (lane >= 32) ? t11 : t10;
    }

    // ================= UP: level 7 =================
    float e7[2], ps7[2];
#pragma unroll
    for (int q = 0; q < 2; ++q) {
        const int bi = 128 + lane + 64 * q;
        float kx = pkx[bi], ky = pky[bi], kz = pkz[bi], kw = pkw[bi];
        float e = bf2f(ev7[q]);
        e7[q] = e;
        float dm = lse2_2(kz - e, kw + e + da7[q])
                 - lse2_2(kx - e, ky + e + da7[q]);
        ps7[q] = dm + __shfl_xor(dm, 1, 64);
    }
    float da6;
    {
        const int s = (2 * lane) & 63;
        float t0 = __shfl(ps7[0], s, 64), t1 = __shfl(ps7[1], s, 64);
        da6 = (lane >= 32) ? t1 : t0;
    }

    const float e6 = bf2f(ev6s);
    float eup[6];
#pragma unroll
    for (int lvl = 0; lvl < 6; ++lvl) eup[lvl] = bf2f(evu[lvl]);

    // ================= UP: shuffle levels 5..0 =================
    float daS[6];
    {
        float da_cur = da6, e_cur = e6;
        int cb = 64;
#pragma unroll
        for (int lvl = 5; lvl >= 0; --lvl) {
            const int idx = cb + lane;
            float kx = pkx[idx], ky = pky[idx], kz = pkz[idx], kw = pkw[idx];
            float m0 = lse2_2(kx - e_cur, ky + e_cur + da_cur);
            float m1 = lse2_2(kz - e_cur, kw + e_cur + da_cur);
            float dm = m1 - m0;
            float da_new = __shfl(dm, (2 * lane) & 63, 64)
                         + __shfl(dm, (2 * lane + 1) & 63, 64);
            da_cur = da_new;
            e_cur  = eup[lvl];
            daS[lvl] = da_new;
            cb = (1 << lvl);
        }
    }

    // ================= DOWN: shuffle levels 0..5 =================
    float db_cur = 0.f;
#pragma unroll
    for (int lvl = 0; lvl < 6; ++lvl) {
        const int np = 1 << lvl;
        const int idx = 2 * np + lane;
        float kx = pkx[idx], ky = pky[idx], kz = pkz[idx], kw = pkw[idx];
        if (lane < np)
            __builtin_nontemporal_store(
                sigmoid2(2.f * eup[lvl] + daS[lvl] + db_cur), &orow[np - 1 + lane]);
        float pdb = __shfl(db_cur, lane >> 1, 64);
        float pe  = __shfl(eup[lvl], lane >> 1, 64);
        db_cur = lse2_2(-pe + ky, pe + pdb + kw) - lse2_2(-pe + kx, pe + pdb + kz);
    }
    const float db6 = db_cur;
    __builtin_nontemporal_store(sigmoid2(2.f * e6 + da6 + db6), &orow[63 + lane]);

    // ================= DOWN: 6 -> 7 =================
    float db7[2];
#pragma unroll
    for (int q = 0; q < 2; ++q) {
        const int u = (lane >> 1) + 32 * q;
        const int bi = 128 + lane + 64 * q;
        float kx = pkx[bi], ky = pky[bi], kz = pkz[bi], kw = pkw[bi];
        float pe  = __shfl(e6, u, 64);
        float pdb = __shfl(db6, u, 64);
        db7[q] = lse2_2(-pe + ky, pe + pdb + kw) - lse2_2(-pe + kx, pe + pdb + kz);
        __builtin_nontemporal_store(
            sigmoid2(2.f * e7[q] + da7[q] + db7[q]), &orow[127 + lane + 64 * q]);
    }

    // ================= DOWN: 7 -> 8 =================
    float db8[4];
#pragma unroll
    for (int q = 0; q < 4; ++q) {
        const int u  = (lane >> 1) + 32 * q;
        const int sl = u & 63;
        const int bi = 256 + lane + 64 * q;
        float kx = pkx[bi], ky = pky[bi], kz = pkz[bi], kw = pkw[bi];
        float pe  = __shfl(e7[q >> 1], sl, 64);
        float pdb = __shfl(db7[q >> 1], sl, 64);
        db8[q] = lse2_2(-pe + ky, pe + pdb + kw) - lse2_2(-pe + kx, pe + pdb + kz);
        __builtin_nontemporal_store(
            sigmoid2(2.f * e8[q] + da8[q] + db8[q]), &orow[255 + lane + 64 * q]);
    }

    // ================= DOWN: 8 -> 9 (in-lane parents) =================
    float db9[4][2];
#pragma unroll
    for (int q = 0; q < 4; ++q) {
        const int j = lane + 64 * q;
        const int p0 = 512 + j, p1 = 768 + j;
        const float lp0 = -e8[q], lp1 = e8[q] + db8[q];
        db9[q][0] = lse2_2(lp0 + pky[p0], lp1 + pkw[p0])
                  - lse2_2(lp0 + pkx[p0], lp1 + pkz[p0]);
        db9[q][1] = lse2_2(lp0 + pky[p1], lp1 + pkw[p1])
                  - lse2_2(lp0 + pkx[p1], lp1 + pkz[p1]);
        __builtin_nontemporal_store(
            sigmoid2(2.f * e9[q][0] + da9[q][0] + db9[q][0]),
            &orow[511 + 2 * lane + 128 * q]);
        __builtin_nontemporal_store(
            sigmoid2(2.f * e9[q][1] + da9[q][1] + db9[q][1]),
            &orow[511 + 2 * lane + 128 * q + 1]);
    }

    // ================= DOWN: 9 -> 10 (leaves, in-lane parents) =========
#pragma unroll
    for (int q = 0; q < 4; ++q) {
        const int j = lane + 64 * q;
#pragma unroll
        for (int r = 0; r < 4; ++r) {
            const int pos = 1024 + r * 256 + j;
            const float kx = pkx[pos], ky = pky[pos], kz = pkz[pos], kw = pkw[pos];
            const float pe = e9[q][r >> 1], pdb = db9[q][r >> 1];
            float db = lse2_2(-pe + ky, pe + pdb + kw)
                     - lse2_2(-pe + kx, pe + pdb + kz);
            __builtin_nontemporal_store(
                sigmoid2(2.f * el[q][r] + db),
                &orow[1023 + 4 * lane + 256 * q + r]);
        }
    }
}

// ---------------------------------------------------------------------------
// Fallback CRF (block-per-row, LDS, raw pairs, in-place on d_out)
// ---------------------------------------------------------------------------
__global__ __launch_bounds__(64) void crf_fallback_kernel(
    const float* __restrict__ pairs, float* __restrict__ eo)
{
    __shared__ float se[C_DIM];
    __shared__ float da[1023];
    __shared__ float P0[1024];
    __shared__ float P1[1024];

    const int row  = blockIdx.x;
    const int lane = threadIdx.x;
    float* erow = eo + (size_t)row * C_DIM;

    for (int c = lane; c < C_DIM; c += 64) se[c] = erow[c] * LOG2E;
    __syncthreads();

    float* cur = P0; float* nxt = P1;
    for (int l = DEPTH - 1; l >= 1; --l) {
        const int np = 1 << (l - 1);
        const int pg0 = np - 1;
        const bool leaf = (l == DEPTH - 1);
        for (int i = lane; i < np; i += 64) {
            const int p = pg0 + i;
            float a0 = 0.f, a1 = 0.f;
#pragma unroll
            for (int s = 0; s < 2; ++s) {
                const int c = 2 * p + 1 + s;
                const int jc = 2 * i + s;
                float ca0 = 0.f, ca1 = 0.f;
                if (!leaf) { ca0 = cur[jc * 2]; ca1 = cur[jc * 2 + 1]; }
                const float l0 = -se[c] + ca0;
                const float l1 =  se[c] + ca1;
                float4 pe = *(const float4*)(pairs + ((size_t)p * C_DIM + c) * 4);
                pe.x *= LOG2E; pe.y *= LOG2E; pe.z *= LOG2E; pe.w *= LOG2E;
                a0 += lse2_2(pe.x + l0, pe.y + l1);
                a1 += lse2_2(pe.z + l0, pe.w + l1);
            }
            nxt[i * 2] = a0; nxt[i * 2 + 1] = a1;
            da[p] = a1 - a0;
        }
        __syncthreads();
        float* t = cur; cur = nxt; nxt = t;
    }
    if (lane == 0) erow[0] = sigmoid2(2.f * se[0] + da[0]);

    float* bcur = P0; float* bnxt = P1;
    for (int l = 1; l <= DEPTH - 1; ++l) {
        const int nc = 1 << l;
        const int cg0 = nc - 1;
        const bool top = (l == 1), last = (l == DEPTH - 1);
        for (int j = lane; j < nc; j += 64) {
            const int c = cg0 + j;
            const int p = (c - 1) >> 1;
            const int ip = j >> 1;
            float b0 = 0.f, b1 = 0.f;
            if (!top) { b0 = bcur[ip * 2]; b1 = bcur[ip * 2 + 1]; }
            const float lp0 = -se[p] + b0;
            const float lp1 =  se[p] + b1;
            float4 pe = *(const float4*)(pairs + ((size_t)p * C_DIM + c) * 4);
            pe.x *= LOG2E; pe.y *= LOG2E; pe.z *= LOG2E; pe.w *= LOG2E;
            const float bc0 = lse2_2(lp0 + pe.x, lp1 + pe.z);
            const float bc1 = lse2_2(lp0 + pe.y, lp1 + pe.w);
            if (!last) { bnxt[j * 2] = bc0; bnxt[j * 2 + 1] = bc1; }
            float d = 2.f * se[c] + (bc1 - bc0);
            if (c < 1023) d += da[c];
            erow[c] = sigmoid2(d);
        }
        __syncthreads();
        float* t = bcur; bcur = bnxt; bnxt = t;
    }
}

// ---------------------------------------------------------------------------
extern "C" void kernel_launch(void* const* d_in, const int* in_sizes, int n_in,
                              void* d_out, int out_size, void* d_ws, size_t ws_size,
                              hipStream_t stream) {
    const float* x     = (const float*)d_in[0];
    const float* w     = (const float*)d_in[1];
    const float* bias  = (const float*)d_in[2];
    const float* pairs = (const float*)d_in[3];
    float* out = (float*)d_out;

    // ws layout: xb | wb | pk (SoA 4 planes f32) | eb (bf16 padded emissions)
    unsigned short* xb = (unsigned short*)d_ws;
    unsigned short* wb = xb + (size_t)XTOT;
    float* pkbuf = (float*)(wb + (size_t)WTOT);
    unsigned short* ebuf = (unsigned short*)(pkbuf + 4 * 2048);

    const size_t need = (size_t)(XTOT + WTOT) * 2 + (size_t)4 * 2048 * 4
                      + ((size_t)B_DIM * C_PAD + C_PAD) * 2;   // ~28.8 MiB

    if (ws_size >= need) {
        cvt_pack_kernel<<<(XTOT + WTOT + 2048) / (256 * 4), 256, 0, stream>>>(
            x, w, pairs, xb, wb, pkbuf);
        dim3 ggrid(C_PAD / 128, B_DIM / 128);
        gemm_bf16_kernel<<<ggrid, 256, 0, stream>>>(xb, wb, bias, ebuf);
        crf_wave_kernel<<<B_DIM / 8, 512, 0, stream>>>(pkbuf, ebuf, out);
    } else {
        dim3 ggrid((C_DIM + BNF - 1) / BNF, B_DIM / BMF);
        gemm_f32_kernel<<<ggrid, 256, 0, stream>>>(x, w, bias, out);
        crf_fallback_kernel<<<B_DIM, 64, 0, stream>>>(pairs, out);
    }
}

// Round 14
// 61.919 us; speedup vs baseline: 1.1179x; 1.1179x over previous
//
#include <hip/hip_runtime.h>
#include <math.h>

// Problem dims (fixed by the reference)
#define B_DIM 4096
#define F_DIM 1024
#define C_DIM 2047
#define C_PAD 2048
#define DEPTH 11

#define LOG2E 1.4426950408889634f

typedef __attribute__((ext_vector_type(8))) short bf16x8;
typedef __attribute__((ext_vector_type(4))) float f32x4;

#define AS1(p) ((const __attribute__((address_space(1))) void*)(p))
#define AS3(p) ((__attribute__((address_space(3))) void*)(p))

#define XTOT (B_DIM * F_DIM)          // 4194304
#define WTOT (C_PAD * F_DIM)          // 2097152

// ---------------------------------------------------------------------------
// bf16 helpers (RNE)
// ---------------------------------------------------------------------------
__device__ __forceinline__ unsigned short f2bf(float f) {
    unsigned int u = __float_as_uint(f);
    unsigned int r = (u + 0x7fffu + ((u >> 16) & 1u)) >> 16;
    return (unsigned short)r;
}
__device__ __forceinline__ float bf2f(unsigned short u) {
    return __uint_as_float(((unsigned int)u) << 16);
}

// pk position remap (bank-conflict-free LDS layout), n = node+1 in [1,2048):
//   n < 512           : pos = n                      (scalar-access levels)
//   512 <= n < 1024   : pos = 512 + (n&1)*256 + ((n-512)>>1)    (level 9)
//   1024 <= n         : pos = 1024 + (n&3)*256 + ((n-1024)>>2)  (leaves)
__device__ __forceinline__ int pk_pos(int n) {
    if (n < 512) return n;
    if (n < 1024) return 512 + (n & 1) * 256 + ((n - 512) >> 1);
    return 1024 + (n & 3) * 256 + ((n - 1024) >> 2);
}

// ---------------------------------------------------------------------------
// Fused convert + pack:
//   x (B,F) f32 -> xb bf16 ; w (C,F) f32 -> wb bf16 (padded to C_PAD rows)
//   pairs tree edges -> pk SoA [4][2048], de-interleaved layout, * LOG2E
// ---------------------------------------------------------------------------
__global__ __launch_bounds__(256) void cvt_pack_kernel(
    const float* __restrict__ x, const float* __restrict__ w,
    const float* __restrict__ pairs,
    unsigned short* __restrict__ xb, unsigned short* __restrict__ wb,
    float* __restrict__ pk)
{
    const int i = (blockIdx.x * 256 + threadIdx.x) * 4;
    if (i < XTOT) {
        float4 v = *(const float4*)(x + i);
        ushort4 h;
        h.x = f2bf(v.x); h.y = f2bf(v.y); h.z = f2bf(v.z); h.w = f2bf(v.w);
        *(ushort4*)(xb + i) = h;
    } else if (i < XTOT + WTOT) {
        const int j = i - XTOT;                    // < WTOT
        const int row = j >> 10;                   // F = 1024
        ushort4 h = {0, 0, 0, 0};
        if (row < C_DIM) {
            float4 v = *(const float4*)(w + j);
            h.x = f2bf(v.x); h.y = f2bf(v.y); h.z = f2bf(v.z); h.w = f2bf(v.w);
        }
        *(ushort4*)(wb + j) = h;
    } else {
        const int c0 = i - XTOT - WTOT;            // 0..2044 step 4
#pragma unroll
        for (int t = 0; t < 4; ++t) {
            const int c = c0 + t;
            if (c >= 1 && c < C_DIM) {
                const int p = (c - 1) >> 1;
                float4 v = *(const float4*)(pairs + ((size_t)p * C_DIM + c) * 4);
                const int pos = pk_pos(c + 1);
                pk[pos]        = v.x * LOG2E;
                pk[pos + 2048] = v.y * LOG2E;
                pk[pos + 4096] = v.z * LOG2E;
                pk[pos + 6144] = v.w * LOG2E;
            }
        }
    }
}

// ---------------------------------------------------------------------------
// MFMA GEMM, 2-phase pipeline:
//   eb[r*2048 + c + 1] = bf16( (x @ W^T + bias)[r,c] * LOG2E )
// 128x128 tile, K-tile = 64, double-buffered LDS, one barrier per K-tile.
// Conflict-free chunk swizzle s(row)=(row>>1)&3.
// XCD mapping: each XCD owns an 8bm x 8bn chunk (4 MB working set = L2 size).
// Plain stores for eb (NT 2-byte stores caused 3x write amplification, r13).
// ---------------------------------------------------------------------------
__global__ __launch_bounds__(256) void gemm_bf16_kernel(
    const unsigned short* __restrict__ xb, const unsigned short* __restrict__ wb,
    const float* __restrict__ bias, unsigned short* __restrict__ eb)
{
    __shared__ unsigned short smem[2][2][2][4096];

    const int tid  = threadIdx.x;
    const int lane = tid & 63;
    const int wave = tid >> 6;
    const int wr = wave >> 1, wc = wave & 1;

    const int lin   = blockIdx.x + blockIdx.y * gridDim.x;   // 0..511
    const int xcd   = lin & 7, local = lin >> 3;             // 8 x 64
    const int bm = (xcd >> 1) * 8 + (local >> 3);            // 0..31
    const int bn = (xcd & 1) * 8 + (local & 7);              // 0..15

    f32x4 acc[4][4] = {};

    const int r0 = tid >> 2,       c0 = tid & 3;
    const int r1 = 64 + (tid >> 2);
    const int sc0 = ((c0 ^ ((r0 >> 1) & 3)) << 3);
    const int sc1 = ((c0 ^ ((r1 >> 1) & 3)) << 3);

    const size_t arow0 = (size_t)(bm * 128 + r0) * F_DIM;
    const size_t arow1 = (size_t)(bm * 128 + r1) * F_DIM;
    const size_t brow0 = (size_t)(bn * 128 + r0) * F_DIM;
    const size_t brow1 = (size_t)(bn * 128 + r1) * F_DIM;

    const int lb0 = wave * 512;
    const int lb1 = 2048 + wave * 512;

    const int fra = wr * 64 + (lane & 15);
    const int frb = wc * 64 + (lane & 15);
    const int kc  = lane >> 4;

#define STAGE(buf, kt)                                                          \
    {                                                                           \
        const int kbase = (kt) * 64;                                            \
        _Pragma("unroll")                                                       \
        for (int ks = 0; ks < 2; ++ks) {                                        \
            const int k0 = kbase + ks * 32;                                     \
            __builtin_amdgcn_global_load_lds(AS1(xb + arow0 + k0 + sc0),        \
                AS3(&smem[buf][0][ks][lb0]), 16, 0, 0);                         \
            __builtin_amdgcn_global_load_lds(AS1(xb + arow1 + k0 + sc1),        \
                AS3(&smem[buf][0][ks][lb1]), 16, 0, 0);                         \
            __builtin_amdgcn_global_load_lds(AS1(wb + brow0 + k0 + sc0),        \
                AS3(&smem[buf][1][ks][lb0]), 16, 0, 0);                         \
            __builtin_amdgcn_global_load_lds(AS1(wb + brow1 + k0 + sc1),        \
                AS3(&smem[buf][1][ks][lb1]), 16, 0, 0);                         \
        }                                                                       \
    }

    const int NT = F_DIM / 64;   // 16
    STAGE(0, 0);
    __syncthreads();

    for (int kt = 0; kt < NT; ++kt) {
        const int cur = kt & 1;
        if (kt + 1 < NT) STAGE(cur ^ 1, kt + 1);

#pragma unroll
        for (int ks = 0; ks < 2; ++ks) {
            bf16x8 af[4], bfr[4];
#pragma unroll
            for (int m = 0; m < 4; ++m) {
                const int row = fra + m * 16;
                af[m] = *(const bf16x8*)(&smem[cur][0][ks]
                        [row * 32 + ((kc ^ ((row >> 1) & 3)) << 3)]);
            }
#pragma unroll
            for (int n = 0; n < 4; ++n) {
                const int row = frb + n * 16;
                bfr[n] = *(const bf16x8*)(&smem[cur][1][ks]
                        [row * 32 + ((kc ^ ((row >> 1) & 3)) << 3)]);
            }
#pragma unroll
            for (int m = 0; m < 4; ++m)
#pragma unroll
                for (int n = 0; n < 4; ++n)
                    acc[m][n] = __builtin_amdgcn_mfma_f32_16x16x32_bf16(
                        af[m], bfr[n], acc[m][n], 0, 0, 0);
        }
        __syncthreads();
    }
#undef STAGE

    const int colbase = bn * 128 + wc * 64 + (lane & 15);
    const int rowbase = bm * 128 + wr * 64 + ((lane >> 4) << 2);
#pragma unroll
    for (int m = 0; m < 4; ++m)
#pragma unroll
        for (int n = 0; n < 4; ++n) {
            const int gc = colbase + n * 16;
            if (gc < C_DIM) {
                const float bv = bias[gc];
#pragma unroll
                for (int r = 0; r < 4; ++r)
                    eb[(size_t)(rowbase + m * 16 + r) * C_PAD + gc + 1] =
                        f2bf((acc[m][n][r] + bv) * LOG2E);
            }
        }
}

// ---------------------------------------------------------------------------
// Fallback f32 GEMM (only if ws too small) — writes d_out directly
// ---------------------------------------------------------------------------
#define BMF 64
#define BNF 64
#define BKF 16

__global__ __launch_bounds__(256) void gemm_f32_kernel(
    const float* __restrict__ x, const float* __restrict__ w,
    const float* __restrict__ bias, float* __restrict__ e)
{
    __shared__ float As[BKF][BMF];
    __shared__ float Bs[BKF][BNF];
    const int bn = blockIdx.x, bm = blockIdx.y;
    const int tid = threadIdx.x;
    const int tx = tid & 15, ty = tid >> 4;
    const int m0 = ty * 4, n0 = tx * 4;
    const int lrow = tid >> 2, lc4 = (tid & 3) * 4;
    const int gm = bm * BMF + lrow;
    const int gn = bn * BNF + lrow;
    const bool wvalid = (gn < C_DIM);
    const float* xp = x + (size_t)gm * F_DIM + lc4;
    const float* wp = wvalid ? (w + (size_t)gn * F_DIM + lc4) : w;
    float acc[4][4] = {};
    for (int k0 = 0; k0 < F_DIM; k0 += BKF) {
        float4 av = *(const float4*)(xp + k0);
        float4 bv = make_float4(0.f, 0.f, 0.f, 0.f);
        if (wvalid) bv = *(const float4*)(wp + k0);
        As[lc4 + 0][lrow] = av.x; As[lc4 + 1][lrow] = av.y;
        As[lc4 + 2][lrow] = av.z; As[lc4 + 3][lrow] = av.w;
        Bs[lc4 + 0][lrow] = bv.x; Bs[lc4 + 1][lrow] = bv.y;
        Bs[lc4 + 2][lrow] = bv.z; Bs[lc4 + 3][lrow] = bv.w;
        __syncthreads();
#pragma unroll
        for (int k = 0; k < BKF; ++k) {
            float4 a = *(const float4*)&As[k][m0];
            float4 b = *(const float4*)&Bs[k][n0];
            acc[0][0] += a.x * b.x; acc[0][1] += a.x * b.y; acc[0][2] += a.x * b.z; acc[0][3] += a.x * b.w;
            acc[1][0] += a.y * b.x; acc[1][1] += a.y * b.y; acc[1][2] += a.y * b.z; acc[1][3] += a.y * b.w;
            acc[2][0] += a.z * b.x; acc[2][1] += a.z * b.y; acc[2][2] += a.z * b.z; acc[2][3] += a.z * b.w;
            acc[3][0] += a.w * b.x; acc[3][1] += a.w * b.y; acc[3][2] += a.w * b.z; acc[3][3] += a.w * b.w;
        }
        __syncthreads();
    }
    const int gmo = bm * BMF + m0, gno = bn * BNF + n0;
#pragma unroll
    for (int i = 0; i < 4; ++i)
#pragma unroll
        for (int j = 0; j < 4; ++j) {
            int n = gno + j;
            if (n < C_DIM) e[(size_t)(gmo + i) * C_DIM + n] = acc[i][j] + bias[n];
        }
}

// ---------------------------------------------------------------------------
// Tree-CRF: ONE ROW PER WAVE, 8 waves/block (512 thr), grid 512.
// pk staged once per block into LDS (32 KB, de-interleaved layout) — all LDS
// reads are stride-4B across lanes (2-way = conflict-free).
// Emissions arrive PRE-SCALED by log2e. Plain stores (NT regressed, r13).
// ---------------------------------------------------------------------------
__device__ __forceinline__ float lse2_2(float a, float b) {
    float m = fmaxf(a, b);
    return m + __log2f(1.f + exp2f(fminf(a, b) - m));
}
__device__ __forceinline__ float sigmoid2(float d) {
    return __builtin_amdgcn_rcpf(1.f + exp2f(-d));
}

__global__ __launch_bounds__(512) void crf_wave_kernel(
    const float* __restrict__ pk,          // SoA [4][2048], de-interleaved
    const unsigned short* __restrict__ eb, // (B, C_PAD) bf16 emissions*LOG2E, +1
    float* __restrict__ out)               // (B, C_DIM) probabilities
{
    __shared__ float spk[4 * 2048];        // 32 KB: planes x,y,z,w

    const int tid  = threadIdx.x;
#pragma unroll
    for (int t = 0; t < 4; ++t) {
        const int idx = t * 2048 + tid * 4;
        *(float4*)(spk + idx) = *(const float4*)(pk + idx);
    }
    __syncthreads();

    const int lane = tid & 63;
    const int row  = blockIdx.x * 8 + (tid >> 6);
    const unsigned short* ebr = eb + (size_t)row * C_PAD;
    float* orow = out + (size_t)row * C_DIM;

    const float* pkx = spk;
    const float* pky = spk + 2048;
    const float* pkz = spk + 4096;
    const float* pkw = spk + 6144;

    // ---------------- ALL emission loads upfront (independent) --------------
    ushort4 evl[4]; ushort2 ev9[4];
    unsigned short ev8[4], ev7[2], ev6s, evu[6];
#pragma unroll
    for (int q = 0; q < 4; ++q)
        evl[q] = *(const ushort4*)(ebr + 1024 + 4 * lane + 256 * q);
#pragma unroll
    for (int q = 0; q < 4; ++q)
        ev9[q] = *(const ushort2*)(ebr + 512 + 2 * lane + 128 * q);
#pragma unroll
    for (int q = 0; q < 4; ++q) ev8[q] = ebr[256 + lane + 64 * q];
#pragma unroll
    for (int q = 0; q < 2; ++q) ev7[q] = ebr[128 + lane + 64 * q];
    ev6s = ebr[64 + lane];
#pragma unroll
    for (int lvl = 0; lvl < 6; ++lvl) evu[lvl] = ebr[(1 << lvl) + lane];

    // ================= UP: leaves (level 10) =================
    // leaf edge n = 1024+4j+r, j = lane+64q -> spk pos 1024 + r*256 + j
    float el[4][4], da9[4][2];
#pragma unroll
    for (int q = 0; q < 4; ++q) {
        const int j = lane + 64 * q;
        float er[4] = {bf2f(evl[q].x), bf2f(evl[q].y), bf2f(evl[q].z), bf2f(evl[q].w)};
        float dm[4];
#pragma unroll
        for (int r = 0; r < 4; ++r) {
            const int pos = 1024 + r * 256 + j;
            const float kx = pkx[pos], ky = pky[pos], kz = pkz[pos], kw = pkw[pos];
            el[q][r] = er[r];
            dm[r] = lse2_2(kz - er[r], kw + er[r])
                  - lse2_2(kx - er[r], ky + er[r]);
        }
        da9[q][0] = dm[0] + dm[1];
        da9[q][1] = dm[2] + dm[3];
    }

    // ================= UP: level 9 =================
    // edge n = 512+2j+r, j = lane+64q -> spk pos 512 + r*256 + j
    float e9[4][2], da8[4];
#pragma unroll
    for (int q = 0; q < 4; ++q) {
        const int j = lane + 64 * q;
        const int p0 = 512 + j, p1 = 768 + j;
        float e0 = bf2f(ev9[q].x), e1 = bf2f(ev9[q].y);
        e9[q][0] = e0; e9[q][1] = e1;
        float dm0 = lse2_2(pkz[p0] - e0, pkw[p0] + e0 + da9[q][0])
                  - lse2_2(pkx[p0] - e0, pky[p0] + e0 + da9[q][0]);
        float dm1 = lse2_2(pkz[p1] - e1, pkw[p1] + e1 + da9[q][1])
                  - lse2_2(pkx[p1] - e1, pky[p1] + e1 + da9[q][1]);
        da8[q] = dm0 + dm1;
    }

    // ================= UP: level 8 =================
    float e8[4], ps8[4];
#pragma unroll
    for (int q = 0; q < 4; ++q) {
        const int bi = 256 + lane + 64 * q;
        float kx = pkx[bi], ky = pky[bi], kz = pkz[bi], kw = pkw[bi];
        float e = bf2f(ev8[q]);
        e8[q] = e;
        float dm = lse2_2(kz - e, kw + e + da8[q])
                 - lse2_2(kx - e, ky + e + da8[q]);
        ps8[q] = dm + __shfl_xor(dm, 1, 64);
    }
    float da7[2];
    {
        const int s = (2 * lane) & 63;
        float t00 = __shfl(ps8[0], s, 64), t01 = __shfl(ps8[1], s, 64);
        float t10 = __shfl(ps8[2], s, 64), t11 = __shfl(ps8[3], s, 64);
        da7[0] = (lane >= 32) ? t01 : t00;
        da7[1] = (lane >= 32) ? t11 : t10;
    }

    // ================= UP: level 7 =================
    float e7[2], ps7[2];
#pragma unroll
    for (int q = 0; q < 2; ++q) {
        const int bi = 128 + lane + 64 * q;
        float kx = pkx[bi], ky = pky[bi], kz = pkz[bi], kw = pkw[bi];
        float e = bf2f(ev7[q]);
        e7[q] = e;
        float dm = lse2_2(kz - e, kw + e + da7[q])
                 - lse2_2(kx - e, ky + e + da7[q]);
        ps7[q] = dm + __shfl_xor(dm, 1, 64);
    }
    float da6;
    {
        const int s = (2 * lane) & 63;
        float t0 = __shfl(ps7[0], s, 64), t1 = __shfl(ps7[1], s, 64);
        da6 = (lane >= 32) ? t1 : t0;
    }

    const float e6 = bf2f(ev6s);
    float eup[6];
#pragma unroll
    for (int lvl = 0; lvl < 6; ++lvl) eup[lvl] = bf2f(evu[lvl]);

    // ================= UP: shuffle levels 5..0 =================
    float daS[6];
    {
        float da_cur = da6, e_cur = e6;
        int cb = 64;
#pragma unroll
        for (int lvl = 5; lvl >= 0; --lvl) {
            const int idx = cb + lane;
            float kx = pkx[idx], ky = pky[idx], kz = pkz[idx], kw = pkw[idx];
            float m0 = lse2_2(kx - e_cur, ky + e_cur + da_cur);
            float m1 = lse2_2(kz - e_cur, kw + e_cur + da_cur);
            float dm = m1 - m0;
            float da_new = __shfl(dm, (2 * lane) & 63, 64)
                         + __shfl(dm, (2 * lane + 1) & 63, 64);
            da_cur = da_new;
            e_cur  = eup[lvl];
            daS[lvl] = da_new;
            cb = (1 << lvl);
        }
    }

    // ================= DOWN: shuffle levels 0..5 =================
    float db_cur = 0.f;
#pragma unroll
    for (int lvl = 0; lvl < 6; ++lvl) {
        const int np = 1 << lvl;
        const int idx = 2 * np + lane;
        float kx = pkx[idx], ky = pky[idx], kz = pkz[idx], kw = pkw[idx];
        if (lane < np)
            orow[np - 1 + lane] = sigmoid2(2.f * eup[lvl] + daS[lvl] + db_cur);
        float pdb = __shfl(db_cur, lane >> 1, 64);
        float pe  = __shfl(eup[lvl], lane >> 1, 64);
        db_cur = lse2_2(-pe + ky, pe + pdb + kw) - lse2_2(-pe + kx, pe + pdb + kz);
    }
    const float db6 = db_cur;
    orow[63 + lane] = sigmoid2(2.f * e6 + da6 + db6);

    // ================= DOWN: 6 -> 7 =================
    float db7[2];
#pragma unroll
    for (int q = 0; q < 2; ++q) {
        const int u = (lane >> 1) + 32 * q;
        const int bi = 128 + lane + 64 * q;
        float kx = pkx[bi], ky = pky[bi], kz = pkz[bi], kw = pkw[bi];
        float pe  = __shfl(e6, u, 64);
        float pdb = __shfl(db6, u, 64);
        db7[q] = lse2_2(-pe + ky, pe + pdb + kw) - lse2_2(-pe + kx, pe + pdb + kz);
        orow[127 + lane + 64 * q] = sigmoid2(2.f * e7[q] + da7[q] + db7[q]);
    }

    // ================= DOWN: 7 -> 8 =================
    float db8[4];
#pragma unroll
    for (int q = 0; q < 4; ++q) {
        const int u  = (lane >> 1) + 32 * q;
        const int sl = u & 63;
        const int bi = 256 + lane + 64 * q;
        float kx = pkx[bi], ky = pky[bi], kz = pkz[bi], kw = pkw[bi];
        float pe  = __shfl(e7[q >> 1], sl, 64);
        float pdb = __shfl(db7[q >> 1], sl, 64);
        db8[q] = lse2_2(-pe + ky, pe + pdb + kw) - lse2_2(-pe + kx, pe + pdb + kz);
        orow[255 + lane + 64 * q] = sigmoid2(2.f * e8[q] + da8[q] + db8[q]);
    }

    // ================= DOWN: 8 -> 9 (in-lane parents) =================
    float db9[4][2];
#pragma unroll
    for (int q = 0; q < 4; ++q) {
        const int j = lane + 64 * q;
        const int p0 = 512 + j, p1 = 768 + j;
        const float lp0 = -e8[q], lp1 = e8[q] + db8[q];
        db9[q][0] = lse2_2(lp0 + pky[p0], lp1 + pkw[p0])
                  - lse2_2(lp0 + pkx[p0], lp1 + pkz[p0]);
        db9[q][1] = lse2_2(lp0 + pky[p1], lp1 + pkw[p1])
                  - lse2_2(lp0 + pkx[p1], lp1 + pkz[p1]);
        orow[511 + 2 * lane + 128 * q]     = sigmoid2(2.f * e9[q][0] + da9[q][0] + db9[q][0]);
        orow[511 + 2 * lane + 128 * q + 1] = sigmoid2(2.f * e9[q][1] + da9[q][1] + db9[q][1]);
    }

    // ================= DOWN: 9 -> 10 (leaves, in-lane parents) =========
#pragma unroll
    for (int q = 0; q < 4; ++q) {
        const int j = lane + 64 * q;
#pragma unroll
        for (int r = 0; r < 4; ++r) {
            const int pos = 1024 + r * 256 + j;
            const float kx = pkx[pos], ky = pky[pos], kz = pkz[pos], kw = pkw[pos];
            const float pe = e9[q][r >> 1], pdb = db9[q][r >> 1];
            float db = lse2_2(-pe + ky, pe + pdb + kw)
                     - lse2_2(-pe + kx, pe + pdb + kz);
            orow[1023 + 4 * lane + 256 * q + r] = sigmoid2(2.f * el[q][r] + db);
        }
    }
}

// ---------------------------------------------------------------------------
// Fallback CRF (block-per-row, LDS, raw pairs, in-place on d_out)
// ---------------------------------------------------------------------------
__global__ __launch_bounds__(64) void crf_fallback_kernel(
    const float* __restrict__ pairs, float* __restrict__ eo)
{
    __shared__ float se[C_DIM];
    __shared__ float da[1023];
    __shared__ float P0[1024];
    __shared__ float P1[1024];

    const int row  = blockIdx.x;
    const int lane = threadIdx.x;
    float* erow = eo + (size_t)row * C_DIM;

    for (int c = lane; c < C_DIM; c += 64) se[c] = erow[c] * LOG2E;
    __syncthreads();

    float* cur = P0; float* nxt = P1;
    for (int l = DEPTH - 1; l >= 1; --l) {
        const int np = 1 << (l - 1);
        const int pg0 = np - 1;
        const bool leaf = (l == DEPTH - 1);
        for (int i = lane; i < np; i += 64) {
            const int p = pg0 + i;
            float a0 = 0.f, a1 = 0.f;
#pragma unroll
            for (int s = 0; s < 2; ++s) {
                const int c = 2 * p + 1 + s;
                const int jc = 2 * i + s;
                float ca0 = 0.f, ca1 = 0.f;
                if (!leaf) { ca0 = cur[jc * 2]; ca1 = cur[jc * 2 + 1]; }
                const float l0 = -se[c] + ca0;
                const float l1 =  se[c] + ca1;
                float4 pe = *(const float4*)(pairs + ((size_t)p * C_DIM + c) * 4);
                pe.x *= LOG2E; pe.y *= LOG2E; pe.z *= LOG2E; pe.w *= LOG2E;
                a0 += lse2_2(pe.x + l0, pe.y + l1);
                a1 += lse2_2(pe.z + l0, pe.w + l1);
            }
            nxt[i * 2] = a0; nxt[i * 2 + 1] = a1;
            da[p] = a1 - a0;
        }
        __syncthreads();
        float* t = cur; cur = nxt; nxt = t;
    }
    if (lane == 0) erow[0] = sigmoid2(2.f * se[0] + da[0]);

    float* bcur = P0; float* bnxt = P1;
    for (int l = 1; l <= DEPTH - 1; ++l) {
        const int nc = 1 << l;
        const int cg0 = nc - 1;
        const bool top = (l == 1), last = (l == DEPTH - 1);
        for (int j = lane; j < nc; j += 64) {
            const int c = cg0 + j;
            const int p = (c - 1) >> 1;
            const int ip = j >> 1;
            float b0 = 0.f, b1 = 0.f;
            if (!top) { b0 = bcur[ip * 2]; b1 = bcur[ip * 2 + 1]; }
            const float lp0 = -se[p] + b0;
            const float lp1 =  se[p] + b1;
            float4 pe = *(const float4*)(pairs + ((size_t)p * C_DIM + c) * 4);
            pe.x *= LOG2E; pe.y *= LOG2E; pe.z *= LOG2E; pe.w *= LOG2E;
            const float bc0 = lse2_2(lp0 + pe.x, lp1 + pe.z);
            const float bc1 = lse2_2(lp0 + pe.y, lp1 + pe.w);
            if (!last) { bnxt[j * 2] = bc0; bnxt[j * 2 + 1] = bc1; }
            float d = 2.f * se[c] + (bc1 - bc0);
            if (c < 1023) d += da[c];
            erow[c] = sigmoid2(d);
        }
        __syncthreads();
        float* t = bcur; bcur = bnxt; bnxt = t;
    }
}

// ---------------------------------------------------------------------------
extern "C" void kernel_launch(void* const* d_in, const int* in_sizes, int n_in,
                              void* d_out, int out_size, void* d_ws, size_t ws_size,
                              hipStream_t stream) {
    const float* x     = (const float*)d_in[0];
    const float* w     = (const float*)d_in[1];
    const float* bias  = (const float*)d_in[2];
    const float* pairs = (const float*)d_in[3];
    float* out = (float*)d_out;

    // ws layout: xb | wb | pk (SoA 4 planes f32) | eb (bf16 padded emissions)
    unsigned short* xb = (unsigned short*)d_ws;
    unsigned short* wb = xb + (size_t)XTOT;
    float* pkbuf = (float*)(wb + (size_t)WTOT);
    unsigned short* ebuf = (unsigned short*)(pkbuf + 4 * 2048);

    const size_t need = (size_t)(XTOT + WTOT) * 2 + (size_t)4 * 2048 * 4
                      + ((size_t)B_DIM * C_PAD + C_PAD) * 2;   // ~28.8 MiB

    if (ws_size >= need) {
        cvt_pack_kernel<<<(XTOT + WTOT + 2048) / (256 * 4), 256, 0, stream>>>(
            x, w, pairs, xb, wb, pkbuf);
        dim3 ggrid(C_PAD / 128, B_DIM / 128);
        gemm_bf16_kernel<<<ggrid, 256, 0, stream>>>(xb, wb, bias, ebuf);
        crf_wave_kernel<<<B_DIM / 8, 512, 0, stream>>>(pkbuf, ebuf, out);
    } else {
        dim3 ggrid((C_DIM + BNF - 1) / BNF, B_DIM / BMF);
        gemm_f32_kernel<<<ggrid, 256, 0, stream>>>(x, w, bias, out);
        crf_fallback_kernel<<<B_DIM, 64, 0, stream>>>(pairs, out);
    }
}